// Round 11
// baseline (6509.491 us; speedup 1.0000x reference)
//
#include <hip/hip_runtime.h>
#include <hip/hip_bf16.h>

#define SEQ 2048
#define NB  64

typedef _Float16 f16x8 __attribute__((ext_vector_type(8)));
typedef _Float16 f16x4 __attribute__((ext_vector_type(4)));
typedef float    f32x4 __attribute__((ext_vector_type(4)));

__device__ __forceinline__ float fast_sigmoid(float x) {
    float e = __builtin_amdgcn_exp2f(-1.4426950408889634f * x);
    return __builtin_amdgcn_rcpf(1.f + e);
}
__device__ __forceinline__ float fast_tanh(float x) {
    float e = __builtin_amdgcn_exp2f(2.8853900817779268f * x);
    return fmaf(-2.f, __builtin_amdgcn_rcpf(1.f + e), 1.f);
}

// Split 8 consecutive f32 into f16 hi/lo fragments (hi+lo ~ 22 mantissa bits).
__device__ __forceinline__ void split8(const float* p4, f16x8& hi, f16x8& lo) {
    float4 a0 = *(const float4*)p4, a1 = *(const float4*)(p4 + 4);
    float av[8] = {a0.x,a0.y,a0.z,a0.w,a1.x,a1.y,a1.z,a1.w};
    #pragma unroll
    for (int e = 0; e < 8; ++e) {
        _Float16 h = (_Float16)av[e];
        hi[e] = h; lo[e] = (_Float16)(av[e] - (float)h);
    }
}

// gx fragment layout (per chunk step s):
//   off = s*65536 + (dir*4 + bg16)*8192 + gt*256 + lane*4 + reg   (f32)
// = 16x16x32 MFMA C layout: n = gt*16+(lane&15), m = bg16*16+(lane>>4)*4+reg.

// ---------------------------------------------------------------------------
// Recurrence body. 8 WGs (4 bg x 2 dir), 512 thr. Wave w: gate tiles gt=8T+w,
// cells kidx=16w+col. K=128 over 4 k-slices, 3-term split f16.
// ROUND-11 CHANGE: the 3 split terms accumulate into 3 INDEPENDENT
// accumulator sets (P init=gx, Q,R init=0; summed in the epilogue) ->
// 12 independent 4-deep MFMA chains per wave instead of 4 x 12-deep,
// hiding MFMA C-operand dependency latency.
// PHASE 0: write h as f16 hi+lo planes (feeds gemm1). PHASE 1: hi only (out1).
// ---------------------------------------------------------------------------
template<int PHASE>
__device__ __forceinline__ void rec_body(
    const float* __restrict__ gx,
    const float* __restrict__ Whf, const float* __restrict__ Whr,
    _Float16* __restrict__ o1, _Float16* __restrict__ o2,
    float* __restrict__ state, int tq0, int steps, int first,
    int bg, int dir)
{
    __builtin_amdgcn_s_setprio(2);     // protect the serial critical path
    const float* Wh = dir ? Whr : Whf;
    const int tid  = threadIdx.x;
    const int w    = tid >> 6;
    const int lane = tid & 63;
    const int col  = lane & 15;
    const int kg   = lane >> 4;
    const int kidx = 16*w + col;

    f16x8 Bhi[4][4], Blo[4][4];
    #pragma unroll
    for (int T = 0; T < 4; ++T) {
        const float* wr = Wh + (size_t)((8*T + w)*16 + col) * 128;
        #pragma unroll
        for (int ks = 0; ks < 4; ++ks)
            split8(wr + ks*32 + kg*8, Bhi[T][ks], Blo[T][ks]);
    }

    __shared__ f16x8 HhiA[256], HloA[256], HhiB[256], HloB[256];

    float cr[4], hr[4];
    float* stbase = state + ((size_t)dir*4 + bg) * 4096;
    #pragma unroll
    for (int r = 0; r < 4; ++r) {
        const int m = kg*4 + r;
        float hv = first ? 0.f : stbase[m*128 + kidx];
        float cv = first ? 0.f : stbase[2048 + m*128 + kidx];
        hr[r] = hv; cr[r] = cv;
        _Float16 hhi = (_Float16)hv;
        _Float16 hlo = (_Float16)(hv - (float)hhi);
        const int el = m*128 + (((kidx>>3) ^ m) & 15)*8 + (kidx & 7);
        ((_Float16*)HhiA)[el] = hhi;
        ((_Float16*)HloA)[el] = hlo;
    }
    __syncthreads();

    const float* gxp = gx + (size_t)(dir*4 + bg)*8192 + (size_t)lane*4;

    f32x4 gA[4], gB[4];
    #pragma unroll
    for (int T = 0; T < 4; ++T) {
        gA[T] = *(const f32x4*)(gxp + (8*T + w)*256);
        gB[T] = *(const f32x4*)(gxp + (8*T + w)*256 + 65536);
    }

    auto rec_step = [&](f32x4 (&G)[4], f16x8 (&RHI)[256], f16x8 (&RLO)[256],
                        f16x8 (&WHI)[256], f16x8 (&WLO)[256], int STEP) {
        f16x8 Ah[4], Al[4];
        #pragma unroll
        for (int ks = 0; ks < 4; ++ks) {
            const int u = col*16 + ((ks*4 + kg) ^ col);
            Ah[ks] = RHI[u];
            Al[ks] = RLO[u];
        }
        // 12 independent accumulator chains (4-deep each):
        // P_T = gx_T + sum Ah*Bhi ; Q_T = sum Al*Bhi ; R_T = sum Ah*Blo
        f32x4 P0 = G[0], P1 = G[1], P2 = G[2], P3 = G[3];
        f32x4 Q0 = {0,0,0,0}, Q1 = {0,0,0,0}, Q2 = {0,0,0,0}, Q3 = {0,0,0,0};
        f32x4 R0 = {0,0,0,0}, R1 = {0,0,0,0}, R2 = {0,0,0,0}, R3 = {0,0,0,0};
        // prefetch 2 steps ahead, clamped (tail prefetch unused)
        const int ps = (STEP + 2 < steps) ? (STEP + 2) : (steps - 1);
        #pragma unroll
        for (int T = 0; T < 4; ++T)
            G[T] = *(const f32x4*)(gxp + (8*T + w)*256 + (size_t)ps*65536);
        #pragma unroll
        for (int ks = 0; ks < 4; ++ks) {
            P0 = __builtin_amdgcn_mfma_f32_16x16x32_f16(Ah[ks], Bhi[0][ks], P0, 0,0,0);
            Q0 = __builtin_amdgcn_mfma_f32_16x16x32_f16(Al[ks], Bhi[0][ks], Q0, 0,0,0);
            R0 = __builtin_amdgcn_mfma_f32_16x16x32_f16(Ah[ks], Blo[0][ks], R0, 0,0,0);
            P1 = __builtin_amdgcn_mfma_f32_16x16x32_f16(Ah[ks], Bhi[1][ks], P1, 0,0,0);
            Q1 = __builtin_amdgcn_mfma_f32_16x16x32_f16(Al[ks], Bhi[1][ks], Q1, 0,0,0);
            R1 = __builtin_amdgcn_mfma_f32_16x16x32_f16(Ah[ks], Blo[1][ks], R1, 0,0,0);
            P2 = __builtin_amdgcn_mfma_f32_16x16x32_f16(Ah[ks], Bhi[2][ks], P2, 0,0,0);
            Q2 = __builtin_amdgcn_mfma_f32_16x16x32_f16(Al[ks], Bhi[2][ks], Q2, 0,0,0);
            R2 = __builtin_amdgcn_mfma_f32_16x16x32_f16(Ah[ks], Blo[2][ks], R2, 0,0,0);
            P3 = __builtin_amdgcn_mfma_f32_16x16x32_f16(Ah[ks], Bhi[3][ks], P3, 0,0,0);
            Q3 = __builtin_amdgcn_mfma_f32_16x16x32_f16(Al[ks], Bhi[3][ks], Q3, 0,0,0);
            R3 = __builtin_amdgcn_mfma_f32_16x16x32_f16(Ah[ks], Blo[3][ks], R3, 0,0,0);
        }
        f32x4 acc0 = (P0 + Q0) + R0;
        f32x4 acc1 = (P1 + Q1) + R1;
        f32x4 acc2 = (P2 + Q2) + R2;
        f32x4 acc3 = (P3 + Q3) + R3;
        const int t = dir ? (SEQ-1 - tq0 - STEP) : (tq0 + STEP);
        #pragma unroll
        for (int r = 0; r < 4; ++r) {
            float iv = fast_sigmoid(acc0[r]);
            float fv = fast_sigmoid(acc1[r]);
            float gv = fast_tanh(acc2[r]);
            float ov = fast_sigmoid(acc3[r]);
            float cv = fmaf(fv, cr[r], iv * gv);
            cr[r] = cv;
            float hv = ov * fast_tanh(cv);
            hr[r] = hv;
            _Float16 hhi = (_Float16)hv;
            _Float16 hlo = (_Float16)(hv - (float)hhi);
            const int m = kg*4 + r;
            const int el = m*128 + (((kidx>>3) ^ m) & 15)*8 + (kidx & 7);
            ((_Float16*)WHI)[el] = hhi;
            ((_Float16*)WLO)[el] = hlo;
            const size_t oi = ((size_t)t*NB + (bg*16 + m))*256 + dir*128 + kidx;
            o1[oi] = hhi;                      // fire-and-forget
            if constexpr (PHASE == 0) o2[oi] = hlo;
        }
        asm volatile("s_waitcnt lgkmcnt(0)" ::: "memory");
        __builtin_amdgcn_s_barrier();
        asm volatile("" ::: "memory");
    };

    for (int step = 0; step < steps; step += 2) {
        rec_step(gA, HhiA, HloA, HhiB, HloB, step);
        rec_step(gB, HhiB, HloB, HhiA, HloA, step + 1);
    }

    #pragma unroll
    for (int r = 0; r < 4; ++r) {
        const int m = kg*4 + r;
        stbase[m*128 + kidx] = hr[r];
        stbase[2048 + m*128 + kidx] = cr[r];
    }
    __builtin_amdgcn_s_setprio(0);
}

// ---------------------------------------------------------------------------
// Fused chunk step. blockIdx < nrec: recurrence WG for chunk q (reads gxR).
// blockIdx >= nrec: GEMM WG for chunk q+1 (writes gxW). 512 thr everywhere;
// GEMM WGs: 8 waves covering two time slots (4 waves each). Input weights are
// read as f32 and split to f16 hi/lo inline.
// PHASE 0: gemm0 (A = x f32, K=64). PHASE 1: gemm1 (A = h0 hi/lo, K=256).
// ---------------------------------------------------------------------------
template<int PHASE>
__global__ __launch_bounds__(512, 2) void megastep(
    const void* __restrict__ Agm, const _Float16* __restrict__ AloG,
    const float* __restrict__ WgF, const float* __restrict__ WgR,
    const float* __restrict__ bF, const float* __restrict__ bR,
    float* __restrict__ gxW,
    const float* __restrict__ gxR,
    const float* __restrict__ Whf, const float* __restrict__ Whr,
    _Float16* __restrict__ o1, _Float16* __restrict__ o2,
    float* __restrict__ state,
    int nrec, int tq0r, int steps, int first,
    int tq0g)
{
    const int bid = blockIdx.x;
    if (bid < nrec) {
        rec_body<PHASE>(gxR, Whf, Whr, o1, o2, state, tq0r, steps, first,
                        bid & 3, bid >> 2);
        return;
    }
    // ---- GEMM part (chunk at tq0g) ----
    const int g    = bid - nrec;
    const int nblk = g & 7;
    const int rr   = g >> 3;
    const int half = steps >> 1;
    const int spair = rr % half;
    const int dir   = rr / half;
    const int tid  = threadIdx.x;
    const int lane = tid & 63;
    const int w8   = tid >> 6;
    const int s    = spair*2 + (w8 >> 2);      // chunk-local time slot
    const int wave = w8 & 3;
    const int t    = dir ? (SEQ - 1 - tq0g - s) : (tq0g + s);
    const float* W      = dir ? WgR : WgF;
    const float* bias   = dir ? bR  : bF;
    const int col = lane & 15, kg = lane >> 4;

    if constexpr (PHASE == 0) {
        const float* x = (const float*)Agm;
        const int n0 = nblk * 64;
        f32x4 acc[4] = {{0,0,0,0},{0,0,0,0},{0,0,0,0},{0,0,0,0}};
        #pragma unroll
        for (int ks = 0; ks < 2; ++ks) {
            f16x8 ahi, alo;
            split8(x + ((size_t)t*NB + wave*16 + col) * 64 + ks*32 + kg*8, ahi, alo);
            #pragma unroll
            for (int nt = 0; nt < 4; ++nt) {
                f16x8 bhi, blo;
                split8(W + (size_t)(n0 + nt*16 + col) * 64 + ks*32 + kg*8, bhi, blo);
                acc[nt] = __builtin_amdgcn_mfma_f32_16x16x32_f16(ahi, bhi, acc[nt], 0,0,0);
                acc[nt] = __builtin_amdgcn_mfma_f32_16x16x32_f16(ahi, blo, acc[nt], 0,0,0);
                acc[nt] = __builtin_amdgcn_mfma_f32_16x16x32_f16(alo, bhi, acc[nt], 0,0,0);
            }
        }
        #pragma unroll
        for (int nt = 0; nt < 4; ++nt) {
            const int n = n0 + nt*16 + col;
            const float bv = bias[n];
            f32x4 v = {acc[nt][0]+bv, acc[nt][1]+bv, acc[nt][2]+bv, acc[nt][3]+bv};
            size_t fi = (size_t)s*65536 + (size_t)(dir*4 + wave)*8192
                      + (size_t)(nblk*4 + nt)*256 + lane*4;
            *(f32x4*)(gxW + fi) = v;
        }
    } else {
        const _Float16* Ahi = (const _Float16*)Agm;
        const int wm = wave >> 1, wn = wave & 1;
        const int n0 = nblk * 64 + wn * 32;
        f32x4 acc[2][2] = {{{0,0,0,0},{0,0,0,0}},{{0,0,0,0},{0,0,0,0}}};
        #pragma unroll
        for (int ks = 0; ks < 8; ++ks) {
            f16x8 ahi[2], alo[2];
            #pragma unroll
            for (int mt = 0; mt < 2; ++mt) {
                const size_t arow = (size_t)t*NB + wm*32 + mt*16 + col;
                ahi[mt] = *(const f16x8*)(Ahi  + arow*256 + ks*32 + kg*8);
                alo[mt] = *(const f16x8*)(AloG + arow*256 + ks*32 + kg*8);
            }
            #pragma unroll
            for (int nt = 0; nt < 2; ++nt) {
                f16x8 bhi, blo;
                split8(W + (size_t)(n0 + nt*16 + col) * 256 + ks*32 + kg*8, bhi, blo);
                #pragma unroll
                for (int mt = 0; mt < 2; ++mt) {
                    acc[mt][nt] = __builtin_amdgcn_mfma_f32_16x16x32_f16(ahi[mt], bhi, acc[mt][nt], 0,0,0);
                    acc[mt][nt] = __builtin_amdgcn_mfma_f32_16x16x32_f16(ahi[mt], blo, acc[mt][nt], 0,0,0);
                    acc[mt][nt] = __builtin_amdgcn_mfma_f32_16x16x32_f16(alo[mt], bhi, acc[mt][nt], 0,0,0);
                }
            }
        }
        #pragma unroll
        for (int mt = 0; mt < 2; ++mt)
            #pragma unroll
            for (int nt = 0; nt < 2; ++nt) {
                const int n = n0 + nt*16 + col;
                const float bv = bias[n];
                f32x4 v = {acc[mt][nt][0]+bv, acc[mt][nt][1]+bv,
                           acc[mt][nt][2]+bv, acc[mt][nt][3]+bv};
                size_t fi = (size_t)s*65536 + (size_t)(dir*4 + (wm*2+mt))*8192
                          + (size_t)(nblk*4 + wn*2 + nt)*256 + lane*4;
                *(f32x4*)(gxW + fi) = v;
            }
    }
}

// ---------------------------------------------------------------------------
// Head: y[m] = sum_j out1[m][j]*w_out[j] + b_out. One wave per row.
// Overwrites ALL of d_out (which also served as rec-state scratch).
// ---------------------------------------------------------------------------
__global__ __launch_bounds__(256) void final_lin(
    const _Float16* __restrict__ out1,
    const float* __restrict__ wout, const float* __restrict__ bout,
    float* __restrict__ y)
{
    const int lane = threadIdx.x & 63;
    const int wave = threadIdx.x >> 6;
    const int row  = blockIdx.x * 4 + wave;
    f16x4 u = *(const f16x4*)(out1 + (size_t)row*256 + lane*4);
    float4 wv = *(const float4*)(wout + lane*4);
    float s = (float)u[0]*wv.x + (float)u[1]*wv.y + (float)u[2]*wv.z + (float)u[3]*wv.w;
    #pragma unroll
    for (int off = 32; off > 0; off >>= 1) s += __shfl_down(s, off, 64);
    if (lane == 0) y[row] = s + bout[0];
}

extern "C" void kernel_launch(void* const* d_in, const int* in_sizes, int n_in,
                              void* d_out, int out_size, void* d_ws, size_t ws_size,
                              hipStream_t stream) {
    const float* x      = (const float*)d_in[0];
    const float* wih_f0 = (const float*)d_in[1];
    const float* whh_f0 = (const float*)d_in[2];
    const float* b_f0   = (const float*)d_in[3];
    const float* wih_r0 = (const float*)d_in[4];
    const float* whh_r0 = (const float*)d_in[5];
    const float* b_r0   = (const float*)d_in[6];
    const float* wih_f1 = (const float*)d_in[7];
    const float* whh_f1 = (const float*)d_in[8];
    const float* b_f1   = (const float*)d_in[9];
    const float* wih_r1 = (const float*)d_in[10];
    const float* whh_r1 = (const float*)d_in[11];
    const float* b_r1   = (const float*)d_in[12];
    const float* w_out  = (const float*)d_in[13];
    const float* b_out  = (const float*)d_in[14];

    const size_t hB      = (size_t)SEQ*NB*256*2;   // 67.1 MB per f16 h-plane
    const size_t gxStepB = 65536ull*4;             // 256 KB per gx step

    // Workspace: h0hi | h0lo | out1 | gx0 | gx1. rec state lives in d_out
    // (512 KB; final_lin overwrites all of it at the end).
    const int cand[5] = {256, 128, 64, 32, 16};
    int Tc = 16;
    for (int i = 0; i < 5; ++i)
        if (3*hB + 2*(size_t)cand[i]*gxStepB <= ws_size) { Tc = cand[i]; break; }
    const int nq = SEQ / Tc;

    char* p = (char*)d_ws;
    _Float16* h0hi = (_Float16*)p; p += hB;
    _Float16* h0lo = (_Float16*)p; p += hB;
    _Float16* out1 = (_Float16*)p; p += hB;
    float*    gx0  = (float*)p;    p += (size_t)Tc*gxStepB;
    float*    gx1  = (float*)p;
    float*    state = (float*)d_out;               // 128 KB of the 512 KB out buf

    const int ngemm = 8 * Tc;
    float* gxb[2] = {gx0, gx1};

    // ---- Layer 0: gemm0 prologue, then fused rec-L0(q) || gemm0(q+1) ----
    megastep<0><<<ngemm, 512, 0, stream>>>(
        x, nullptr, wih_f0, wih_r0, b_f0, b_r0,
        gxb[0], nullptr, nullptr, nullptr, nullptr, nullptr, nullptr,
        0, 0, Tc, 0, 0);
    for (int q = 0; q < nq; ++q) {
        const int nxt = (q + 1 < nq);
        megastep<0><<<8 + (nxt ? ngemm : 0), 512, 0, stream>>>(
            x, nullptr, wih_f0, wih_r0, b_f0, b_r0,
            gxb[(q+1)&1], gxb[q&1], whh_f0, whh_r0, h0hi, h0lo, state,
            8, q*Tc, Tc, q==0, (q+1)*Tc);
    }
    // ---- Layer 1: gemm1 prologue, then fused rec-L1(q) || gemm1(q+1) ----
    megastep<1><<<ngemm, 512, 0, stream>>>(
        h0hi, h0lo, wih_f1, wih_r1, b_f1, b_r1,
        gxb[0], nullptr, nullptr, nullptr, nullptr, nullptr, nullptr,
        0, 0, Tc, 0, 0);
    for (int q = 0; q < nq; ++q) {
        const int nxt = (q + 1 < nq);
        megastep<1><<<8 + (nxt ? ngemm : 0), 512, 0, stream>>>(
            h0hi, h0lo, wih_f1, wih_r1, b_f1, b_r1,
            gxb[(q+1)&1], gxb[q&1], whh_f1, whh_r1, out1, nullptr, state,
            8, q*Tc, Tc, q==0, (q+1)*Tc);
    }
    final_lin<<<SEQ*NB/4, 256, 0, stream>>>(out1, w_out, b_out, (float*)d_out);
}

// Round 12
// 5651.620 us; speedup vs baseline: 1.1518x; 1.1518x over previous
//
#include <hip/hip_runtime.h>
#include <hip/hip_bf16.h>

#define SEQ 2048
#define NB  64

typedef _Float16 f16x8 __attribute__((ext_vector_type(8)));
typedef _Float16 f16x4 __attribute__((ext_vector_type(4)));
typedef float    f32x4 __attribute__((ext_vector_type(4)));

__device__ __forceinline__ float fast_sigmoid(float x) {
    float e = __builtin_amdgcn_exp2f(-1.4426950408889634f * x);
    return __builtin_amdgcn_rcpf(1.f + e);
}
__device__ __forceinline__ float fast_tanh(float x) {
    float e = __builtin_amdgcn_exp2f(2.8853900817779268f * x);
    return fmaf(-2.f, __builtin_amdgcn_rcpf(1.f + e), 1.f);
}

// Split 8 consecutive f32 into f16 hi/lo fragments (hi+lo ~ 22 mantissa bits).
__device__ __forceinline__ void split8(const float* p4, f16x8& hi, f16x8& lo) {
    float4 a0 = *(const float4*)p4, a1 = *(const float4*)(p4 + 4);
    float av[8] = {a0.x,a0.y,a0.z,a0.w,a1.x,a1.y,a1.z,a1.w};
    #pragma unroll
    for (int e = 0; e < 8; ++e) {
        _Float16 h = (_Float16)av[e];
        hi[e] = h; lo[e] = (_Float16)(av[e] - (float)h);
    }
}

// gx fragment layout (per chunk step s):
//   off = s*65536 + (dir*4 + bg16)*8192 + gt*256 + lane*4 + reg   (f32)
// = 16x16x32 MFMA C layout: n = gt*16+(lane&15), m = bg16*16+(lane>>4)*4+reg.

// ---------------------------------------------------------------------------
// Recurrence body (round-9 verified math, bit-identical). 8 WGs (4 bg x 2 dir),
// 512 thr. Wave w: gate tiles gt=8T+w, cells kidx=16w+col. K=128, 4 k-slices,
// 3-term split f16, serial accumulation into 4 chains.
// ROUND-12: kernel is __launch_bounds__(512,1) -> 256-VGPR budget so the
// 32 loop-invariant B fragments (128 VGPRs) actually STAY in registers
// instead of being rematerialized (reload + cvt chains) every step.
// PHASE 0: write h as f16 hi+lo planes (feeds gemm1). PHASE 1: hi only (out1).
// ---------------------------------------------------------------------------
template<int PHASE>
__device__ __forceinline__ void rec_body(
    const float* __restrict__ gx,
    const float* __restrict__ Whf, const float* __restrict__ Whr,
    _Float16* __restrict__ o1, _Float16* __restrict__ o2,
    float* __restrict__ state, int tq0, int steps, int first,
    int bg, int dir)
{
    __builtin_amdgcn_s_setprio(2);     // protect the serial critical path
    const float* Wh = dir ? Whr : Whf;
    const int tid  = threadIdx.x;
    const int w    = tid >> 6;
    const int lane = tid & 63;
    const int col  = lane & 15;
    const int kg   = lane >> 4;
    const int kidx = 16*w + col;

    f16x8 Bhi[4][4], Blo[4][4];
    #pragma unroll
    for (int T = 0; T < 4; ++T) {
        const float* wr = Wh + (size_t)((8*T + w)*16 + col) * 128;
        #pragma unroll
        for (int ks = 0; ks < 4; ++ks)
            split8(wr + ks*32 + kg*8, Bhi[T][ks], Blo[T][ks]);
    }

    __shared__ f16x8 HhiA[256], HloA[256], HhiB[256], HloB[256];

    float cr[4], hr[4];
    float* stbase = state + ((size_t)dir*4 + bg) * 4096;
    #pragma unroll
    for (int r = 0; r < 4; ++r) {
        const int m = kg*4 + r;
        float hv = first ? 0.f : stbase[m*128 + kidx];
        float cv = first ? 0.f : stbase[2048 + m*128 + kidx];
        hr[r] = hv; cr[r] = cv;
        _Float16 hhi = (_Float16)hv;
        _Float16 hlo = (_Float16)(hv - (float)hhi);
        const int el = m*128 + (((kidx>>3) ^ m) & 15)*8 + (kidx & 7);
        ((_Float16*)HhiA)[el] = hhi;
        ((_Float16*)HloA)[el] = hlo;
    }
    __syncthreads();

    const float* gxp = gx + (size_t)(dir*4 + bg)*8192 + (size_t)lane*4;

    f32x4 gA[4], gB[4];
    #pragma unroll
    for (int T = 0; T < 4; ++T) {
        gA[T] = *(const f32x4*)(gxp + (8*T + w)*256);
        gB[T] = *(const f32x4*)(gxp + (8*T + w)*256 + 65536);
    }

    auto rec_step = [&](f32x4 (&G)[4], f16x8 (&RHI)[256], f16x8 (&RLO)[256],
                        f16x8 (&WHI)[256], f16x8 (&WLO)[256], int STEP) {
        f16x8 Ah[4], Al[4];
        #pragma unroll
        for (int ks = 0; ks < 4; ++ks) {
            const int u = col*16 + ((ks*4 + kg) ^ col);
            Ah[ks] = RHI[u];
            Al[ks] = RLO[u];
        }
        f32x4 acc0 = G[0], acc1 = G[1], acc2 = G[2], acc3 = G[3];
        // prefetch 2 steps ahead, clamped (tail prefetch unused)
        const int ps = (STEP + 2 < steps) ? (STEP + 2) : (steps - 1);
        #pragma unroll
        for (int T = 0; T < 4; ++T)
            G[T] = *(const f32x4*)(gxp + (8*T + w)*256 + (size_t)ps*65536);
        #pragma unroll
        for (int ks = 0; ks < 4; ++ks) {
            acc0 = __builtin_amdgcn_mfma_f32_16x16x32_f16(Ah[ks], Bhi[0][ks], acc0, 0,0,0);
            acc0 = __builtin_amdgcn_mfma_f32_16x16x32_f16(Al[ks], Bhi[0][ks], acc0, 0,0,0);
            acc0 = __builtin_amdgcn_mfma_f32_16x16x32_f16(Ah[ks], Blo[0][ks], acc0, 0,0,0);
            acc1 = __builtin_amdgcn_mfma_f32_16x16x32_f16(Ah[ks], Bhi[1][ks], acc1, 0,0,0);
            acc1 = __builtin_amdgcn_mfma_f32_16x16x32_f16(Al[ks], Bhi[1][ks], acc1, 0,0,0);
            acc1 = __builtin_amdgcn_mfma_f32_16x16x32_f16(Ah[ks], Blo[1][ks], acc1, 0,0,0);
            acc2 = __builtin_amdgcn_mfma_f32_16x16x32_f16(Ah[ks], Bhi[2][ks], acc2, 0,0,0);
            acc2 = __builtin_amdgcn_mfma_f32_16x16x32_f16(Al[ks], Bhi[2][ks], acc2, 0,0,0);
            acc2 = __builtin_amdgcn_mfma_f32_16x16x32_f16(Ah[ks], Blo[2][ks], acc2, 0,0,0);
            acc3 = __builtin_amdgcn_mfma_f32_16x16x32_f16(Ah[ks], Bhi[3][ks], acc3, 0,0,0);
            acc3 = __builtin_amdgcn_mfma_f32_16x16x32_f16(Al[ks], Bhi[3][ks], acc3, 0,0,0);
            acc3 = __builtin_amdgcn_mfma_f32_16x16x32_f16(Ah[ks], Blo[3][ks], acc3, 0,0,0);
        }
        const int t = dir ? (SEQ-1 - tq0 - STEP) : (tq0 + STEP);
        #pragma unroll
        for (int r = 0; r < 4; ++r) {
            float iv = fast_sigmoid(acc0[r]);
            float fv = fast_sigmoid(acc1[r]);
            float gv = fast_tanh(acc2[r]);
            float ov = fast_sigmoid(acc3[r]);
            float cv = fmaf(fv, cr[r], iv * gv);
            cr[r] = cv;
            float hv = ov * fast_tanh(cv);
            hr[r] = hv;
            _Float16 hhi = (_Float16)hv;
            _Float16 hlo = (_Float16)(hv - (float)hhi);
            const int m = kg*4 + r;
            const int el = m*128 + (((kidx>>3) ^ m) & 15)*8 + (kidx & 7);
            ((_Float16*)WHI)[el] = hhi;
            ((_Float16*)WLO)[el] = hlo;
            const size_t oi = ((size_t)t*NB + (bg*16 + m))*256 + dir*128 + kidx;
            o1[oi] = hhi;                      // fire-and-forget
            if constexpr (PHASE == 0) o2[oi] = hlo;
        }
        asm volatile("s_waitcnt lgkmcnt(0)" ::: "memory");
        __builtin_amdgcn_s_barrier();
        asm volatile("" ::: "memory");
    };

    for (int step = 0; step < steps; step += 2) {
        rec_step(gA, HhiA, HloA, HhiB, HloB, step);
        rec_step(gB, HhiB, HloB, HhiA, HloA, step + 1);
    }

    #pragma unroll
    for (int r = 0; r < 4; ++r) {
        const int m = kg*4 + r;
        stbase[m*128 + kidx] = hr[r];
        stbase[2048 + m*128 + kidx] = cr[r];
    }
    __builtin_amdgcn_s_setprio(0);
}

// ---------------------------------------------------------------------------
// Fused chunk step. blockIdx < nrec: recurrence WG for chunk q (reads gxR).
// blockIdx >= nrec: GEMM WG for chunk q+1 (writes gxW). 512 thr everywhere.
// __launch_bounds__(512,1): 256-VGPR budget (1 block/CU) — keeps the rec
// B fragments register-resident; gemm at 2 waves/SIMD still finishes far
// inside the rec window.
// PHASE 0: gemm0 (A = x f32, K=64). PHASE 1: gemm1 (A = h0 hi/lo, K=256).
// ---------------------------------------------------------------------------
template<int PHASE>
__global__ __launch_bounds__(512, 1) void megastep(
    const void* __restrict__ Agm, const _Float16* __restrict__ AloG,
    const float* __restrict__ WgF, const float* __restrict__ WgR,
    const float* __restrict__ bF, const float* __restrict__ bR,
    float* __restrict__ gxW,
    const float* __restrict__ gxR,
    const float* __restrict__ Whf, const float* __restrict__ Whr,
    _Float16* __restrict__ o1, _Float16* __restrict__ o2,
    float* __restrict__ state,
    int nrec, int tq0r, int steps, int first,
    int tq0g)
{
    const int bid = blockIdx.x;
    if (bid < nrec) {
        rec_body<PHASE>(gxR, Whf, Whr, o1, o2, state, tq0r, steps, first,
                        bid & 3, bid >> 2);
        return;
    }
    // ---- GEMM part (chunk at tq0g) ----
    const int g    = bid - nrec;
    const int nblk = g & 7;
    const int rr   = g >> 3;
    const int half = steps >> 1;
    const int spair = rr % half;
    const int dir   = rr / half;
    const int tid  = threadIdx.x;
    const int lane = tid & 63;
    const int w8   = tid >> 6;
    const int s    = spair*2 + (w8 >> 2);      // chunk-local time slot
    const int wave = w8 & 3;
    const int t    = dir ? (SEQ - 1 - tq0g - s) : (tq0g + s);
    const float* W      = dir ? WgR : WgF;
    const float* bias   = dir ? bR  : bF;
    const int col = lane & 15, kg = lane >> 4;

    if constexpr (PHASE == 0) {
        const float* x = (const float*)Agm;
        const int n0 = nblk * 64;
        f32x4 acc[4] = {{0,0,0,0},{0,0,0,0},{0,0,0,0},{0,0,0,0}};
        #pragma unroll
        for (int ks = 0; ks < 2; ++ks) {
            f16x8 ahi, alo;
            split8(x + ((size_t)t*NB + wave*16 + col) * 64 + ks*32 + kg*8, ahi, alo);
            #pragma unroll
            for (int nt = 0; nt < 4; ++nt) {
                f16x8 bhi, blo;
                split8(W + (size_t)(n0 + nt*16 + col) * 64 + ks*32 + kg*8, bhi, blo);
                acc[nt] = __builtin_amdgcn_mfma_f32_16x16x32_f16(ahi, bhi, acc[nt], 0,0,0);
                acc[nt] = __builtin_amdgcn_mfma_f32_16x16x32_f16(ahi, blo, acc[nt], 0,0,0);
                acc[nt] = __builtin_amdgcn_mfma_f32_16x16x32_f16(alo, bhi, acc[nt], 0,0,0);
            }
        }
        #pragma unroll
        for (int nt = 0; nt < 4; ++nt) {
            const int n = n0 + nt*16 + col;
            const float bv = bias[n];
            f32x4 v = {acc[nt][0]+bv, acc[nt][1]+bv, acc[nt][2]+bv, acc[nt][3]+bv};
            size_t fi = (size_t)s*65536 + (size_t)(dir*4 + wave)*8192
                      + (size_t)(nblk*4 + nt)*256 + lane*4;
            *(f32x4*)(gxW + fi) = v;
        }
    } else {
        const _Float16* Ahi = (const _Float16*)Agm;
        const int wm = wave >> 1, wn = wave & 1;
        const int n0 = nblk * 64 + wn * 32;
        f32x4 acc[2][2] = {{{0,0,0,0},{0,0,0,0}},{{0,0,0,0},{0,0,0,0}}};
        #pragma unroll
        for (int ks = 0; ks < 8; ++ks) {
            f16x8 ahi[2], alo[2];
            #pragma unroll
            for (int mt = 0; mt < 2; ++mt) {
                const size_t arow = (size_t)t*NB + wm*32 + mt*16 + col;
                ahi[mt] = *(const f16x8*)(Ahi  + arow*256 + ks*32 + kg*8);
                alo[mt] = *(const f16x8*)(AloG + arow*256 + ks*32 + kg*8);
            }
            #pragma unroll
            for (int nt = 0; nt < 2; ++nt) {
                f16x8 bhi, blo;
                split8(W + (size_t)(n0 + nt*16 + col) * 256 + ks*32 + kg*8, bhi, blo);
                #pragma unroll
                for (int mt = 0; mt < 2; ++mt) {
                    acc[mt][nt] = __builtin_amdgcn_mfma_f32_16x16x32_f16(ahi[mt], bhi, acc[mt][nt], 0,0,0);
                    acc[mt][nt] = __builtin_amdgcn_mfma_f32_16x16x32_f16(ahi[mt], blo, acc[mt][nt], 0,0,0);
                    acc[mt][nt] = __builtin_amdgcn_mfma_f32_16x16x32_f16(alo[mt], bhi, acc[mt][nt], 0,0,0);
                }
            }
        }
        #pragma unroll
        for (int mt = 0; mt < 2; ++mt)
            #pragma unroll
            for (int nt = 0; nt < 2; ++nt) {
                const int n = n0 + nt*16 + col;
                const float bv = bias[n];
                f32x4 v = {acc[mt][nt][0]+bv, acc[mt][nt][1]+bv,
                           acc[mt][nt][2]+bv, acc[mt][nt][3]+bv};
                size_t fi = (size_t)s*65536 + (size_t)(dir*4 + (wm*2+mt))*8192
                          + (size_t)(nblk*4 + wn*2 + nt)*256 + lane*4;
                *(f32x4*)(gxW + fi) = v;
            }
    }
}

// ---------------------------------------------------------------------------
// Head: y[m] = sum_j out1[m][j]*w_out[j] + b_out. One wave per row.
// Overwrites ALL of d_out (which also served as rec-state scratch).
// ---------------------------------------------------------------------------
__global__ __launch_bounds__(256) void final_lin(
    const _Float16* __restrict__ out1,
    const float* __restrict__ wout, const float* __restrict__ bout,
    float* __restrict__ y)
{
    const int lane = threadIdx.x & 63;
    const int wave = threadIdx.x >> 6;
    const int row  = blockIdx.x * 4 + wave;
    f16x4 u = *(const f16x4*)(out1 + (size_t)row*256 + lane*4);
    float4 wv = *(const float4*)(wout + lane*4);
    float s = (float)u[0]*wv.x + (float)u[1]*wv.y + (float)u[2]*wv.z + (float)u[3]*wv.w;
    #pragma unroll
    for (int off = 32; off > 0; off >>= 1) s += __shfl_down(s, off, 64);
    if (lane == 0) y[row] = s + bout[0];
}

extern "C" void kernel_launch(void* const* d_in, const int* in_sizes, int n_in,
                              void* d_out, int out_size, void* d_ws, size_t ws_size,
                              hipStream_t stream) {
    const float* x      = (const float*)d_in[0];
    const float* wih_f0 = (const float*)d_in[1];
    const float* whh_f0 = (const float*)d_in[2];
    const float* b_f0   = (const float*)d_in[3];
    const float* wih_r0 = (const float*)d_in[4];
    const float* whh_r0 = (const float*)d_in[5];
    const float* b_r0   = (const float*)d_in[6];
    const float* wih_f1 = (const float*)d_in[7];
    const float* whh_f1 = (const float*)d_in[8];
    const float* b_f1   = (const float*)d_in[9];
    const float* wih_r1 = (const float*)d_in[10];
    const float* whh_r1 = (const float*)d_in[11];
    const float* b_r1   = (const float*)d_in[12];
    const float* w_out  = (const float*)d_in[13];
    const float* b_out  = (const float*)d_in[14];

    const size_t hB      = (size_t)SEQ*NB*256*2;   // 67.1 MB per f16 h-plane
    const size_t gxStepB = 65536ull*4;             // 256 KB per gx step

    // Workspace: h0hi | h0lo | out1 | gx0 | gx1. rec state lives in d_out
    // (512 KB; final_lin overwrites all of it at the end).
    const int cand[5] = {256, 128, 64, 32, 16};
    int Tc = 16;
    for (int i = 0; i < 5; ++i)
        if (3*hB + 2*(size_t)cand[i]*gxStepB <= ws_size) { Tc = cand[i]; break; }
    const int nq = SEQ / Tc;

    char* p = (char*)d_ws;
    _Float16* h0hi = (_Float16*)p; p += hB;
    _Float16* h0lo = (_Float16*)p; p += hB;
    _Float16* out1 = (_Float16*)p; p += hB;
    float*    gx0  = (float*)p;    p += (size_t)Tc*gxStepB;
    float*    gx1  = (float*)p;
    float*    state = (float*)d_out;               // 128 KB of the 512 KB out buf

    const int ngemm = 8 * Tc;
    float* gxb[2] = {gx0, gx1};

    // ---- Layer 0: gemm0 prologue, then fused rec-L0(q) || gemm0(q+1) ----
    megastep<0><<<ngemm, 512, 0, stream>>>(
        x, nullptr, wih_f0, wih_r0, b_f0, b_r0,
        gxb[0], nullptr, nullptr, nullptr, nullptr, nullptr, nullptr,
        0, 0, Tc, 0, 0);
    for (int q = 0; q < nq; ++q) {
        const int nxt = (q + 1 < nq);
        megastep<0><<<8 + (nxt ? ngemm : 0), 512, 0, stream>>>(
            x, nullptr, wih_f0, wih_r0, b_f0, b_r0,
            gxb[(q+1)&1], gxb[q&1], whh_f0, whh_r0, h0hi, h0lo, state,
            8, q*Tc, Tc, q==0, (q+1)*Tc);
    }
    // ---- Layer 1: gemm1 prologue, then fused rec-L1(q) || gemm1(q+1) ----
    megastep<1><<<ngemm, 512, 0, stream>>>(
        h0hi, h0lo, wih_f1, wih_r1, b_f1, b_r1,
        gxb[0], nullptr, nullptr, nullptr, nullptr, nullptr, nullptr,
        0, 0, Tc, 0, 0);
    for (int q = 0; q < nq; ++q) {
        const int nxt = (q + 1 < nq);
        megastep<1><<<8 + (nxt ? ngemm : 0), 512, 0, stream>>>(
            h0hi, h0lo, wih_f1, wih_r1, b_f1, b_r1,
            gxb[(q+1)&1], gxb[q&1], whh_f1, whh_r1, out1, nullptr, state,
            8, q*Tc, Tc, q==0, (q+1)*Tc);
    }
    final_lin<<<SEQ*NB/4, 256, 0, stream>>>(out1, w_out, b_out, (float*)d_out);
}

// Round 13
// 5590.035 us; speedup vs baseline: 1.1645x; 1.0110x over previous
//
#include <hip/hip_runtime.h>
#include <hip/hip_bf16.h>

#define SEQ 2048
#define NB  64

typedef _Float16 f16x8 __attribute__((ext_vector_type(8)));
typedef _Float16 f16x4 __attribute__((ext_vector_type(4)));
typedef float    f32x4 __attribute__((ext_vector_type(4)));

__device__ __forceinline__ float fast_sigmoid(float x) {
    float e = __builtin_amdgcn_exp2f(-1.4426950408889634f * x);
    return __builtin_amdgcn_rcpf(1.f + e);
}
__device__ __forceinline__ float fast_tanh(float x) {
    float e = __builtin_amdgcn_exp2f(2.8853900817779268f * x);
    return fmaf(-2.f, __builtin_amdgcn_rcpf(1.f + e), 1.f);
}

// Split 8 consecutive f32 into f16 hi/lo fragments (hi+lo ~ 22 mantissa bits).
__device__ __forceinline__ void split8(const float* p4, f16x8& hi, f16x8& lo) {
    float4 a0 = *(const float4*)p4, a1 = *(const float4*)(p4 + 4);
    float av[8] = {a0.x,a0.y,a0.z,a0.w,a1.x,a1.y,a1.z,a1.w};
    #pragma unroll
    for (int e = 0; e < 8; ++e) {
        _Float16 h = (_Float16)av[e];
        hi[e] = h; lo[e] = (_Float16)(av[e] - (float)h);
    }
}

// Volatile-asm identity pin: the value's definition becomes a volatile asm,
// which the register allocator cannot re-execute -> no rematerialization
// (reload + cvt chains) inside the step loop; value must stay in VGPRs.
__device__ __forceinline__ void pin(f16x8& v) {
    uint4 u = __builtin_bit_cast(uint4, v);
    asm volatile("" : "+v"(u.x), "+v"(u.y), "+v"(u.z), "+v"(u.w));
    v = __builtin_bit_cast(f16x8, u);
}

// gx fragment layout (per chunk step s):
//   off = s*65536 + (dir*4 + bg16)*8192 + gt*256 + lane*4 + reg   (f32)
// = 16x16x32 MFMA C layout: n = gt*16+(lane&15), m = bg16*16+(lane>>4)*4+reg.

// ---------------------------------------------------------------------------
// Recurrence body (round-9 verified math, bit-identical). 8 WGs (4 bg x 2 dir),
// 512 thr. Wave w: gate tiles gt=8T+w, cells kidx=16w+col. K=128, 4 k-slices,
// 3-term split f16, serial accumulation into 4 chains.
// ROUND-13: B fragments pinned via volatile asm so they stay register-resident
// (VGPR budget 256 via __launch_bounds__(512,1)) instead of being
// rematerialized (reload + split) every step — the measured ~1760 cyc/step
// VALU phase matches the remat cost almost exactly.
// PHASE 0: write h as f16 hi+lo planes (feeds gemm1). PHASE 1: hi only (out1).
// ---------------------------------------------------------------------------
template<int PHASE>
__device__ __forceinline__ void rec_body(
    const float* __restrict__ gx,
    const float* __restrict__ Whf, const float* __restrict__ Whr,
    _Float16* __restrict__ o1, _Float16* __restrict__ o2,
    float* __restrict__ state, int tq0, int steps, int first,
    int bg, int dir)
{
    __builtin_amdgcn_s_setprio(2);     // protect the serial critical path
    const float* Wh = dir ? Whr : Whf;
    const int tid  = threadIdx.x;
    const int w    = tid >> 6;
    const int lane = tid & 63;
    const int col  = lane & 15;
    const int kg   = lane >> 4;
    const int kidx = 16*w + col;

    f16x8 Bhi[4][4], Blo[4][4];
    #pragma unroll
    for (int T = 0; T < 4; ++T) {
        const float* wr = Wh + (size_t)((8*T + w)*16 + col) * 128;
        #pragma unroll
        for (int ks = 0; ks < 4; ++ks)
            split8(wr + ks*32 + kg*8, Bhi[T][ks], Blo[T][ks]);
    }
    #pragma unroll
    for (int T = 0; T < 4; ++T)
        #pragma unroll
        for (int ks = 0; ks < 4; ++ks) {
            pin(Bhi[T][ks]);
            pin(Blo[T][ks]);
        }

    __shared__ f16x8 HhiA[256], HloA[256], HhiB[256], HloB[256];

    float cr[4], hr[4];
    float* stbase = state + ((size_t)dir*4 + bg) * 4096;
    #pragma unroll
    for (int r = 0; r < 4; ++r) {
        const int m = kg*4 + r;
        float hv = first ? 0.f : stbase[m*128 + kidx];
        float cv = first ? 0.f : stbase[2048 + m*128 + kidx];
        hr[r] = hv; cr[r] = cv;
        _Float16 hhi = (_Float16)hv;
        _Float16 hlo = (_Float16)(hv - (float)hhi);
        const int el = m*128 + (((kidx>>3) ^ m) & 15)*8 + (kidx & 7);
        ((_Float16*)HhiA)[el] = hhi;
        ((_Float16*)HloA)[el] = hlo;
    }
    __syncthreads();

    const float* gxp = gx + (size_t)(dir*4 + bg)*8192 + (size_t)lane*4;

    f32x4 gA[4], gB[4];
    #pragma unroll
    for (int T = 0; T < 4; ++T) {
        gA[T] = *(const f32x4*)(gxp + (8*T + w)*256);
        gB[T] = *(const f32x4*)(gxp + (8*T + w)*256 + 65536);
    }

    auto rec_step = [&](f32x4 (&G)[4], f16x8 (&RHI)[256], f16x8 (&RLO)[256],
                        f16x8 (&WHI)[256], f16x8 (&WLO)[256], int STEP) {
        f16x8 Ah[4], Al[4];
        #pragma unroll
        for (int ks = 0; ks < 4; ++ks) {
            const int u = col*16 + ((ks*4 + kg) ^ col);
            Ah[ks] = RHI[u];
            Al[ks] = RLO[u];
        }
        f32x4 acc0 = G[0], acc1 = G[1], acc2 = G[2], acc3 = G[3];
        // prefetch 2 steps ahead, clamped (tail prefetch unused)
        const int ps = (STEP + 2 < steps) ? (STEP + 2) : (steps - 1);
        #pragma unroll
        for (int T = 0; T < 4; ++T)
            G[T] = *(const f32x4*)(gxp + (8*T + w)*256 + (size_t)ps*65536);
        #pragma unroll
        for (int ks = 0; ks < 4; ++ks) {
            acc0 = __builtin_amdgcn_mfma_f32_16x16x32_f16(Ah[ks], Bhi[0][ks], acc0, 0,0,0);
            acc0 = __builtin_amdgcn_mfma_f32_16x16x32_f16(Al[ks], Bhi[0][ks], acc0, 0,0,0);
            acc0 = __builtin_amdgcn_mfma_f32_16x16x32_f16(Ah[ks], Blo[0][ks], acc0, 0,0,0);
            acc1 = __builtin_amdgcn_mfma_f32_16x16x32_f16(Ah[ks], Bhi[1][ks], acc1, 0,0,0);
            acc1 = __builtin_amdgcn_mfma_f32_16x16x32_f16(Al[ks], Bhi[1][ks], acc1, 0,0,0);
            acc1 = __builtin_amdgcn_mfma_f32_16x16x32_f16(Ah[ks], Blo[1][ks], acc1, 0,0,0);
            acc2 = __builtin_amdgcn_mfma_f32_16x16x32_f16(Ah[ks], Bhi[2][ks], acc2, 0,0,0);
            acc2 = __builtin_amdgcn_mfma_f32_16x16x32_f16(Al[ks], Bhi[2][ks], acc2, 0,0,0);
            acc2 = __builtin_amdgcn_mfma_f32_16x16x32_f16(Ah[ks], Blo[2][ks], acc2, 0,0,0);
            acc3 = __builtin_amdgcn_mfma_f32_16x16x32_f16(Ah[ks], Bhi[3][ks], acc3, 0,0,0);
            acc3 = __builtin_amdgcn_mfma_f32_16x16x32_f16(Al[ks], Bhi[3][ks], acc3, 0,0,0);
            acc3 = __builtin_amdgcn_mfma_f32_16x16x32_f16(Ah[ks], Blo[3][ks], acc3, 0,0,0);
        }
        const int t = dir ? (SEQ-1 - tq0 - STEP) : (tq0 + STEP);
        #pragma unroll
        for (int r = 0; r < 4; ++r) {
            float iv = fast_sigmoid(acc0[r]);
            float fv = fast_sigmoid(acc1[r]);
            float gv = fast_tanh(acc2[r]);
            float ov = fast_sigmoid(acc3[r]);
            float cv = fmaf(fv, cr[r], iv * gv);
            cr[r] = cv;
            float hv = ov * fast_tanh(cv);
            hr[r] = hv;
            _Float16 hhi = (_Float16)hv;
            _Float16 hlo = (_Float16)(hv - (float)hhi);
            const int m = kg*4 + r;
            const int el = m*128 + (((kidx>>3) ^ m) & 15)*8 + (kidx & 7);
            ((_Float16*)WHI)[el] = hhi;
            ((_Float16*)WLO)[el] = hlo;
            const size_t oi = ((size_t)t*NB + (bg*16 + m))*256 + dir*128 + kidx;
            o1[oi] = hhi;                      // fire-and-forget
            if constexpr (PHASE == 0) o2[oi] = hlo;
        }
        asm volatile("s_waitcnt lgkmcnt(0)" ::: "memory");
        __builtin_amdgcn_s_barrier();
        asm volatile("" ::: "memory");
    };

    for (int step = 0; step < steps; step += 2) {
        rec_step(gA, HhiA, HloA, HhiB, HloB, step);
        rec_step(gB, HhiB, HloB, HhiA, HloA, step + 1);
    }

    #pragma unroll
    for (int r = 0; r < 4; ++r) {
        const int m = kg*4 + r;
        stbase[m*128 + kidx] = hr[r];
        stbase[2048 + m*128 + kidx] = cr[r];
    }
    __builtin_amdgcn_s_setprio(0);
}

// ---------------------------------------------------------------------------
// Fused chunk step. blockIdx < nrec: recurrence WG for chunk q (reads gxR).
// blockIdx >= nrec: GEMM WG for chunk q+1 (writes gxW). 512 thr everywhere.
// __launch_bounds__(512,1): 256-VGPR budget so the pinned rec B fragments
// fit in registers; gemm at 2 waves/SIMD still finishes inside the rec window.
// PHASE 0: gemm0 (A = x f32, K=64). PHASE 1: gemm1 (A = h0 hi/lo, K=256).
// ---------------------------------------------------------------------------
template<int PHASE>
__global__ __launch_bounds__(512, 1) void megastep(
    const void* __restrict__ Agm, const _Float16* __restrict__ AloG,
    const float* __restrict__ WgF, const float* __restrict__ WgR,
    const float* __restrict__ bF, const float* __restrict__ bR,
    float* __restrict__ gxW,
    const float* __restrict__ gxR,
    const float* __restrict__ Whf, const float* __restrict__ Whr,
    _Float16* __restrict__ o1, _Float16* __restrict__ o2,
    float* __restrict__ state,
    int nrec, int tq0r, int steps, int first,
    int tq0g)
{
    const int bid = blockIdx.x;
    if (bid < nrec) {
        rec_body<PHASE>(gxR, Whf, Whr, o1, o2, state, tq0r, steps, first,
                        bid & 3, bid >> 2);
        return;
    }
    // ---- GEMM part (chunk at tq0g) ----
    const int g    = bid - nrec;
    const int nblk = g & 7;
    const int rr   = g >> 3;
    const int half = steps >> 1;
    const int spair = rr % half;
    const int dir   = rr / half;
    const int tid  = threadIdx.x;
    const int lane = tid & 63;
    const int w8   = tid >> 6;
    const int s    = spair*2 + (w8 >> 2);      // chunk-local time slot
    const int wave = w8 & 3;
    const int t    = dir ? (SEQ - 1 - tq0g - s) : (tq0g + s);
    const float* W      = dir ? WgR : WgF;
    const float* bias   = dir ? bR  : bF;
    const int col = lane & 15, kg = lane >> 4;

    if constexpr (PHASE == 0) {
        const float* x = (const float*)Agm;
        const int n0 = nblk * 64;
        f32x4 acc[4] = {{0,0,0,0},{0,0,0,0},{0,0,0,0},{0,0,0,0}};
        #pragma unroll
        for (int ks = 0; ks < 2; ++ks) {
            f16x8 ahi, alo;
            split8(x + ((size_t)t*NB + wave*16 + col) * 64 + ks*32 + kg*8, ahi, alo);
            #pragma unroll
            for (int nt = 0; nt < 4; ++nt) {
                f16x8 bhi, blo;
                split8(W + (size_t)(n0 + nt*16 + col) * 64 + ks*32 + kg*8, bhi, blo);
                acc[nt] = __builtin_amdgcn_mfma_f32_16x16x32_f16(ahi, bhi, acc[nt], 0,0,0);
                acc[nt] = __builtin_amdgcn_mfma_f32_16x16x32_f16(ahi, blo, acc[nt], 0,0,0);
                acc[nt] = __builtin_amdgcn_mfma_f32_16x16x32_f16(alo, bhi, acc[nt], 0,0,0);
            }
        }
        #pragma unroll
        for (int nt = 0; nt < 4; ++nt) {
            const int n = n0 + nt*16 + col;
            const float bv = bias[n];
            f32x4 v = {acc[nt][0]+bv, acc[nt][1]+bv, acc[nt][2]+bv, acc[nt][3]+bv};
            size_t fi = (size_t)s*65536 + (size_t)(dir*4 + wave)*8192
                      + (size_t)(nblk*4 + nt)*256 + lane*4;
            *(f32x4*)(gxW + fi) = v;
        }
    } else {
        const _Float16* Ahi = (const _Float16*)Agm;
        const int wm = wave >> 1, wn = wave & 1;
        const int n0 = nblk * 64 + wn * 32;
        f32x4 acc[2][2] = {{{0,0,0,0},{0,0,0,0}},{{0,0,0,0},{0,0,0,0}}};
        #pragma unroll
        for (int ks = 0; ks < 8; ++ks) {
            f16x8 ahi[2], alo[2];
            #pragma unroll
            for (int mt = 0; mt < 2; ++mt) {
                const size_t arow = (size_t)t*NB + wm*32 + mt*16 + col;
                ahi[mt] = *(const f16x8*)(Ahi  + arow*256 + ks*32 + kg*8);
                alo[mt] = *(const f16x8*)(AloG + arow*256 + ks*32 + kg*8);
            }
            #pragma unroll
            for (int nt = 0; nt < 2; ++nt) {
                f16x8 bhi, blo;
                split8(W + (size_t)(n0 + nt*16 + col) * 256 + ks*32 + kg*8, bhi, blo);
                #pragma unroll
                for (int mt = 0; mt < 2; ++mt) {
                    acc[mt][nt] = __builtin_amdgcn_mfma_f32_16x16x32_f16(ahi[mt], bhi, acc[mt][nt], 0,0,0);
                    acc[mt][nt] = __builtin_amdgcn_mfma_f32_16x16x32_f16(ahi[mt], blo, acc[mt][nt], 0,0,0);
                    acc[mt][nt] = __builtin_amdgcn_mfma_f32_16x16x32_f16(alo[mt], bhi, acc[mt][nt], 0,0,0);
                }
            }
        }
        #pragma unroll
        for (int mt = 0; mt < 2; ++mt)
            #pragma unroll
            for (int nt = 0; nt < 2; ++nt) {
                const int n = n0 + nt*16 + col;
                const float bv = bias[n];
                f32x4 v = {acc[mt][nt][0]+bv, acc[mt][nt][1]+bv,
                           acc[mt][nt][2]+bv, acc[mt][nt][3]+bv};
                size_t fi = (size_t)s*65536 + (size_t)(dir*4 + (wm*2+mt))*8192
                          + (size_t)(nblk*4 + wn*2 + nt)*256 + lane*4;
                *(f32x4*)(gxW + fi) = v;
            }
    }
}

// ---------------------------------------------------------------------------
// Head: y[m] = sum_j out1[m][j]*w_out[j] + b_out. One wave per row.
// Overwrites ALL of d_out (which also served as rec-state scratch).
// ---------------------------------------------------------------------------
__global__ __launch_bounds__(256) void final_lin(
    const _Float16* __restrict__ out1,
    const float* __restrict__ wout, const float* __restrict__ bout,
    float* __restrict__ y)
{
    const int lane = threadIdx.x & 63;
    const int wave = threadIdx.x >> 6;
    const int row  = blockIdx.x * 4 + wave;
    f16x4 u = *(const f16x4*)(out1 + (size_t)row*256 + lane*4);
    float4 wv = *(const float4*)(wout + lane*4);
    float s = (float)u[0]*wv.x + (float)u[1]*wv.y + (float)u[2]*wv.z + (float)u[3]*wv.w;
    #pragma unroll
    for (int off = 32; off > 0; off >>= 1) s += __shfl_down(s, off, 64);
    if (lane == 0) y[row] = s + bout[0];
}

extern "C" void kernel_launch(void* const* d_in, const int* in_sizes, int n_in,
                              void* d_out, int out_size, void* d_ws, size_t ws_size,
                              hipStream_t stream) {
    const float* x      = (const float*)d_in[0];
    const float* wih_f0 = (const float*)d_in[1];
    const float* whh_f0 = (const float*)d_in[2];
    const float* b_f0   = (const float*)d_in[3];
    const float* wih_r0 = (const float*)d_in[4];
    const float* whh_r0 = (const float*)d_in[5];
    const float* b_r0   = (const float*)d_in[6];
    const float* wih_f1 = (const float*)d_in[7];
    const float* whh_f1 = (const float*)d_in[8];
    const float* b_f1   = (const float*)d_in[9];
    const float* wih_r1 = (const float*)d_in[10];
    const float* whh_r1 = (const float*)d_in[11];
    const float* b_r1   = (const float*)d_in[12];
    const float* w_out  = (const float*)d_in[13];
    const float* b_out  = (const float*)d_in[14];

    const size_t hB      = (size_t)SEQ*NB*256*2;   // 67.1 MB per f16 h-plane
    const size_t gxStepB = 65536ull*4;             // 256 KB per gx step

    // Workspace: h0hi | h0lo | out1 | gx0 | gx1. rec state lives in d_out
    // (512 KB; final_lin overwrites all of it at the end).
    const int cand[5] = {256, 128, 64, 32, 16};
    int Tc = 16;
    for (int i = 0; i < 5; ++i)
        if (3*hB + 2*(size_t)cand[i]*gxStepB <= ws_size) { Tc = cand[i]; break; }
    const int nq = SEQ / Tc;

    char* p = (char*)d_ws;
    _Float16* h0hi = (_Float16*)p; p += hB;
    _Float16* h0lo = (_Float16*)p; p += hB;
    _Float16* out1 = (_Float16*)p; p += hB;
    float*    gx0  = (float*)p;    p += (size_t)Tc*gxStepB;
    float*    gx1  = (float*)p;
    float*    state = (float*)d_out;               // 128 KB of the 512 KB out buf

    const int ngemm = 8 * Tc;
    float* gxb[2] = {gx0, gx1};

    // ---- Layer 0: gemm0 prologue, then fused rec-L0(q) || gemm0(q+1) ----
    megastep<0><<<ngemm, 512, 0, stream>>>(
        x, nullptr, wih_f0, wih_r0, b_f0, b_r0,
        gxb[0], nullptr, nullptr, nullptr, nullptr, nullptr, nullptr,
        0, 0, Tc, 0, 0);
    for (int q = 0; q < nq; ++q) {
        const int nxt = (q + 1 < nq);
        megastep<0><<<8 + (nxt ? ngemm : 0), 512, 0, stream>>>(
            x, nullptr, wih_f0, wih_r0, b_f0, b_r0,
            gxb[(q+1)&1], gxb[q&1], whh_f0, whh_r0, h0hi, h0lo, state,
            8, q*Tc, Tc, q==0, (q+1)*Tc);
    }
    // ---- Layer 1: gemm1 prologue, then fused rec-L1(q) || gemm1(q+1) ----
    megastep<1><<<ngemm, 512, 0, stream>>>(
        h0hi, h0lo, wih_f1, wih_r1, b_f1, b_r1,
        gxb[0], nullptr, nullptr, nullptr, nullptr, nullptr, nullptr,
        0, 0, Tc, 0, 0);
    for (int q = 0; q < nq; ++q) {
        const int nxt = (q + 1 < nq);
        megastep<1><<<8 + (nxt ? ngemm : 0), 512, 0, stream>>>(
            h0hi, h0lo, wih_f1, wih_r1, b_f1, b_r1,
            gxb[(q+1)&1], gxb[q&1], whh_f1, whh_r1, out1, nullptr, state,
            8, q*Tc, Tc, q==0, (q+1)*Tc);
    }
    final_lin<<<SEQ*NB/4, 256, 0, stream>>>(out1, w_out, b_out, (float*)d_out);
}